// Round 8
// baseline (2740.716 us; speedup 1.0000x reference)
//
#include <hip/hip_runtime.h>

#define B_ 64
#define T_ 512
#define D_ 512
#define H_ 512
#define NG 2048  // 4H

typedef __attribute__((ext_vector_type(8))) short short8;
typedef __attribute__((ext_vector_type(4))) float floatx4;
typedef __attribute__((ext_vector_type(4))) unsigned int uintx4;

static __device__ __forceinline__ unsigned short f2bf(float f) {
    unsigned int u = __float_as_uint(f);
    return (unsigned short)((u + 0x7FFFu + ((u >> 16) & 1u)) >> 16);  // RNE
}

static __device__ __forceinline__ short8 pack8(float4 a, float4 b) {
    short8 r;
    r[0] = (short)f2bf(a.x); r[1] = (short)f2bf(a.y);
    r[2] = (short)f2bf(a.z); r[3] = (short)f2bf(a.w);
    r[4] = (short)f2bf(b.x); r[5] = (short)f2bf(b.y);
    r[6] = (short)f2bf(b.z); r[7] = (short)f2bf(b.w);
    return r;
}

static __device__ __forceinline__ float sigm(float x) { return 1.0f / (1.0f + __expf(-x)); }
static __device__ __forceinline__ float tanh_(float x) {
    float e = __expf(2.0f * x);
    return 1.0f - 2.0f / (e + 1.0f);
}

// ---- transpose Wi/Wh ([512][2048] f32) -> bf16 [2048][512], LDS-tiled ----
__global__ __launch_bounds__(256) void transpose_w(
    const float* __restrict__ Wi, const float* __restrict__ Wh,
    unsigned short* __restrict__ WiT, unsigned short* __restrict__ WhT)
{
    __shared__ float tile[64][65];
    const float* src = blockIdx.z ? Wh : Wi;
    unsigned short* dst = blockIdx.z ? WhT : WiT;
    const int n0 = blockIdx.x * 64, k0 = blockIdx.y * 64;
    const int cx = threadIdx.x & 63, ry = threadIdx.x >> 6;
#pragma unroll
    for (int i = 0; i < 16; ++i) {
        int k = ry * 16 + i;
        tile[k][cx] = src[(size_t)(k0 + k) * NG + n0 + cx];
    }
    __syncthreads();
#pragma unroll
    for (int i = 0; i < 16; ++i) {
        int n = ry * 16 + i;
        dst[(size_t)(n0 + n) * D_ + k0 + cx] = f2bf(tile[cx][n]);
    }
}

// ---- zx[b][t][4H] (fp16) = flip(x) @ Wi + b ; 128x128 tile, 4 waves ----
__global__ __launch_bounds__(256) void zx_gemm(
    const float* __restrict__ x, const int* __restrict__ lengths,
    const unsigned short* __restrict__ WiT, const float* __restrict__ bias,
    const int* __restrict__ revp, _Float16* __restrict__ zx)
{
    __shared__ unsigned short a_lds[128][40];
    __shared__ unsigned short b_lds[128][40];

    const int mt = blockIdx.x, nt = blockIdx.y;
    const int tid = threadIdx.x;
    const int lane = tid & 63, w = tid >> 6;
    const int wm = w & 1, wn = w >> 1;

    const int b = mt >> 2;
    const int len = lengths[b];
    const int rev = revp[0];

    const int r = tid >> 1;
    const int kh = (tid & 1) << 4;
    const int t = ((mt & 3) << 7) + r;
    const int src_t = rev ? ((T_ - 1 - t + len) & (T_ - 1)) : t;
    const float* arow = x + ((size_t)b * T_ + src_t) * D_;
    const unsigned short* brow = WiT + (size_t)(nt * 128 + r) * D_;

    floatx4 acc[4][4];
#pragma unroll
    for (int i = 0; i < 4; ++i)
#pragma unroll
        for (int j = 0; j < 4; ++j) acc[i][j] = (floatx4){0.f, 0.f, 0.f, 0.f};

    for (int kt = 0; kt < D_ / 32; ++kt) {
        const float4* ap = (const float4*)(arow + kt * 32 + kh);
        float4 a0 = ap[0], a1 = ap[1], a2 = ap[2], a3 = ap[3];
        const uint4* bp = (const uint4*)(brow + kt * 32 + kh);
        uint4 bq0 = bp[0], bq1 = bp[1];
        *(short8*)&a_lds[r][kh]     = pack8(a0, a1);
        *(short8*)&a_lds[r][kh + 8] = pack8(a2, a3);
        *(uint4*)&b_lds[r][kh]     = bq0;
        *(uint4*)&b_lds[r][kh + 8] = bq1;
        __syncthreads();

        short8 af[4], bfr[4];
#pragma unroll
        for (int mi = 0; mi < 4; ++mi)
            af[mi] = *(const short8*)&a_lds[wm * 64 + mi * 16 + (lane & 15)][(lane >> 4) << 3];
#pragma unroll
        for (int ni = 0; ni < 4; ++ni)
            bfr[ni] = *(const short8*)&b_lds[wn * 64 + ni * 16 + (lane & 15)][(lane >> 4) << 3];
#pragma unroll
        for (int mi = 0; mi < 4; ++mi)
#pragma unroll
            for (int ni = 0; ni < 4; ++ni)
                acc[mi][ni] = __builtin_amdgcn_mfma_f32_16x16x32_bf16(af[mi], bfr[ni], acc[mi][ni], 0, 0, 0);
        __syncthreads();
    }

#pragma unroll
    for (int mi = 0; mi < 4; ++mi) {
#pragma unroll
        for (int ni = 0; ni < 4; ++ni) {
            int row = wm * 64 + mi * 16 + ((lane >> 4) << 2);
            int col = nt * 128 + wn * 64 + ni * 16 + (lane & 15);
            float bv = bias[col];
            size_t base = (size_t)(mt * 128 + row) * NG + col;
#pragma unroll
            for (int v = 0; v < 4; ++v)
                zx[base + (size_t)v * NG] = (_Float16)(acc[mi][ni][v] + bv);
        }
    }
}

// ---- persistent LSTM recurrence ----
// 64 blocks = 4 batch-groups(16 batches) x 16 h-blocks(32 units). 4 waves, N-split,
// Wh register-resident. Exchange: self-validating 16B chunks {4 bf16 (batch-quad
// of one unit), step tag, pad} published straight from gate registers, fire-forget.
// Consumer polls its 8 contiguous chunks continuously (detect == data, 1 RTT),
// in-register transpose, ds_write. Loop ordered so poll vmcnt is never poisoned
// by zx prefetch / out stores (those drain under compute).
__global__ __launch_bounds__(256, 1) void lstm_rec(
    const _Float16* __restrict__ zx, const unsigned short* __restrict__ WhT,
    const float* __restrict__ c0, const float* __restrict__ h0,
    const int* __restrict__ lengths, const int* __restrict__ revp,
    float* __restrict__ out, unsigned int* __restrict__ hx)
{
    __shared__ unsigned short h_lds[16][520];   // 16 batches x 512 units (+pad)

    const int bid = blockIdx.x;
    const int gb = bid & 3, gh = bid >> 2;
    const int tid = threadIdx.x;
    const int lane = tid & 63, w = tid >> 6;
    const int b0 = gb * 16, u0 = gh * 32;
    const int rev = revp[0];

    // gates/MFMA map
    const int colh = lane & 15;
    const int rr = (lane >> 4) << 2;   // batch base (MFMA D rows)
    const int cg = colh >> 3;          // gate-pair selector (0:{i,g} 1:{f,o})
    const int cu = colh & 7;
    const int uu = w * 8 + cu;         // unit within block (0..31)
    const int khw = (lane >> 4) << 3;  // k-offset within 32-chunk

    int len_v[4]; float c[4];
#pragma unroll
    for (int v = 0; v < 4; ++v) {
        len_v[v] = lengths[b0 + rr + v];
        c[v] = c0[(size_t)(b0 + rr + v) * H_ + u0 + uu];
    }

    // Wh fragments: bw[kk][ni] for gate = ni*2+cg, unit = u0+uu
    short8 bw[16][2];
#pragma unroll
    for (int ni = 0; ni < 2; ++ni) {
        const unsigned short* src = WhT + (size_t)((ni * 2 + cg) * H_ + u0 + uu) * D_ + khw;
#pragma unroll
        for (int kk = 0; kk < 16; ++kk)
            bw[kk][ni] = *(const short8*)(src + kk * 32);
    }

    float zxv[2][4];
#pragma unroll
    for (int ni = 0; ni < 2; ++ni)
#pragma unroll
        for (int v = 0; v < 4; ++v)
            zxv[ni][v] = (float)zx[((size_t)(b0 + rr + v) * T_) * NG + (ni * 2 + cg) * H_ + u0 + uu];

    // consumer map: thread = (quad q, producer ph, unit-octet o)
    const int q   = tid >> 6;          // 0..3  (== w)
    const int ph  = (tid >> 2) & 15;   // producer gh
    const int o   = tid & 3;           // octet within producer's 32 units
    const int crow = q * 4;
    const int ccol = ph * 32 + o * 8;

    // deferred-out state (flushed next iteration, off the poll path)
    float pend_hn[4], pend_cn[4];
    int have_pend = 0, pend_s = 0;

    for (int s = 0; s < T_; ++s) {
        // ---- stage h(s)[16][512] -> LDS ----
        if (s == 0) {
            const float* hp = h0 + (size_t)(b0 + crow) * H_ + ccol;
#pragma unroll
            for (int v = 0; v < 4; ++v) {
                float4 f0 = *(const float4*)(hp + (size_t)v * H_);
                float4 f1 = *(const float4*)(hp + (size_t)v * H_ + 4);
                *(short8*)&h_lds[crow + v][ccol] = pack8(f0, f1);
            }
        } else {
            // continuous full-width self-validating poll (detect == data)
            const unsigned int* dp =
                hx + ((((unsigned)(s & 1) * 4 + gb) * 16 + ph) << 9) + ((q * 32 + o * 8) << 2);
            uintx4 k0, k1, k2, k3, k4, k5, k6, k7;
            const unsigned int tg = (unsigned int)s;
            for (;;) {
                asm volatile(
                    "global_load_dwordx4 %0, %8, off sc0 sc1\n\t"
                    "global_load_dwordx4 %1, %8, off offset:16 sc0 sc1\n\t"
                    "global_load_dwordx4 %2, %8, off offset:32 sc0 sc1\n\t"
                    "global_load_dwordx4 %3, %8, off offset:48 sc0 sc1\n\t"
                    "global_load_dwordx4 %4, %8, off offset:64 sc0 sc1\n\t"
                    "global_load_dwordx4 %5, %8, off offset:80 sc0 sc1\n\t"
                    "global_load_dwordx4 %6, %8, off offset:96 sc0 sc1\n\t"
                    "global_load_dwordx4 %7, %8, off offset:112 sc0 sc1\n\t"
                    "s_waitcnt vmcnt(0)"
                    : "=&v"(k0), "=&v"(k1), "=&v"(k2), "=&v"(k3),
                      "=&v"(k4), "=&v"(k5), "=&v"(k6), "=&v"(k7)
                    : "v"(dp) : "memory");
                bool ok = (k0[2] == tg) & (k1[2] == tg) & (k2[2] == tg) & (k3[2] == tg) &
                          (k4[2] == tg) & (k5[2] == tg) & (k6[2] == tg) & (k7[2] == tg);
                if (ok) break;
            }
            // in-register transpose: chunk j = unit ccol+j, payload = batch-quad
            uintx4 e0, e1, e2, e3;
            e0[0] = (k0[0] & 0xffffu) | (k1[0] << 16);
            e0[1] = (k2[0] & 0xffffu) | (k3[0] << 16);
            e0[2] = (k4[0] & 0xffffu) | (k5[0] << 16);
            e0[3] = (k6[0] & 0xffffu) | (k7[0] << 16);
            e1[0] = (k0[0] >> 16) | (k1[0] & 0xffff0000u);
            e1[1] = (k2[0] >> 16) | (k3[0] & 0xffff0000u);
            e1[2] = (k4[0] >> 16) | (k5[0] & 0xffff0000u);
            e1[3] = (k6[0] >> 16) | (k7[0] & 0xffff0000u);
            e2[0] = (k0[1] & 0xffffu) | (k1[1] << 16);
            e2[1] = (k2[1] & 0xffffu) | (k3[1] << 16);
            e2[2] = (k4[1] & 0xffffu) | (k5[1] << 16);
            e2[3] = (k6[1] & 0xffffu) | (k7[1] << 16);
            e3[0] = (k0[1] >> 16) | (k1[1] & 0xffff0000u);
            e3[1] = (k2[1] >> 16) | (k3[1] & 0xffff0000u);
            e3[2] = (k4[1] >> 16) | (k5[1] & 0xffff0000u);
            e3[3] = (k6[1] >> 16) | (k7[1] & 0xffff0000u);
            *(uintx4*)&h_lds[crow + 0][ccol] = e0;
            *(uintx4*)&h_lds[crow + 1][ccol] = e1;
            *(uintx4*)&h_lds[crow + 2][ccol] = e2;
            *(uintx4*)&h_lds[crow + 3][ccol] = e3;
        }
        __syncthreads();   // (A) h_lds ready

        // ---- z = h @ Wh (full K per wave, 32 MFMA) ----
        floatx4 acc[2];
        acc[0] = (floatx4){0.f, 0.f, 0.f, 0.f};
        acc[1] = (floatx4){0.f, 0.f, 0.f, 0.f};
#pragma unroll
        for (int kk = 0; kk < 16; ++kk) {
            short8 af = *(const short8*)&h_lds[lane & 15][kk * 32 + khw];
            acc[0] = __builtin_amdgcn_mfma_f32_16x16x32_bf16(af, bw[kk][0], acc[0], 0, 0, 0);
            acc[1] = __builtin_amdgcn_mfma_f32_16x16x32_bf16(af, bw[kk][1], acc[1], 0, 0, 0);
        }
        __syncthreads();   // (B) h_lds reads done (cheap: no fresh vmem outstanding)

        // ---- off-path (drains under gates): flush out(s-1), issue zx(s+1) ----
        if (have_pend) {
#pragma unroll
            for (int v = 0; v < 4; ++v) {
                const int b = b0 + rr + v;
                const int ug = u0 + uu;
                int orig_t = rev ? ((T_ - 1 - pend_s + len_v[v]) & (T_ - 1)) : pend_s;
                if (cg == 0)
                    out[((size_t)b * T_ + orig_t) * H_ + ug] = pend_hn[v];
                if (pend_s == len_v[v] - 1) {
                    size_t fin = (size_t)B_ * T_ * H_;
                    if (cg == 0) out[fin + (size_t)b * H_ + ug] = pend_cn[v];
                    else         out[fin + (size_t)B_ * H_ + (size_t)b * H_ + ug] = pend_hn[v];
                }
            }
        }
        float zxn[2][4];
        if (s + 1 < T_) {
#pragma unroll
            for (int ni = 0; ni < 2; ++ni)
#pragma unroll
                for (int v = 0; v < 4; ++v)
                    zxn[ni][v] = (float)zx[((size_t)(b0 + rr + v) * T_ + s + 1) * NG +
                                           (ni * 2 + cg) * H_ + u0 + uu];
        }

        // ---- gates; publish straight from registers ----
#pragma unroll
        for (int v = 0; v < 4; ++v) {
            float own0 = acc[0][v] + zxv[0][v];        // gate cg
            float own1 = acc[1][v] + zxv[1][v];        // gate 2+cg
            float oth0 = __shfl_xor(own0, 8);          // gate 1-cg
            float oth1 = __shfl_xor(own1, 8);          // gate 3-cg
            float zi = cg ? oth0 : own0;
            float zf = cg ? own0 : oth0;
            float zg = cg ? oth1 : own1;
            float zo = cg ? own1 : oth1;
            float ig = sigm(zi), fg = sigm(zf);
            float gg = tanh_(zg), og = sigm(zo);
            float cn = fg * c[v] + ig * gg;
            float hn = og * tanh_(cn);
            c[v] = cn; pend_cn[v] = cn; pend_hn[v] = hn;
        }
        pend_s = s; have_pend = 1;

        if (cg == 1 && s + 1 < T_) {
            uintx4 ck;
            ck[0] = (unsigned int)f2bf(pend_hn[0]) | ((unsigned int)f2bf(pend_hn[1]) << 16);
            ck[1] = (unsigned int)f2bf(pend_hn[2]) | ((unsigned int)f2bf(pend_hn[3]) << 16);
            ck[2] = (unsigned int)(s + 1); ck[3] = 0u;
            unsigned int* dst = hx + ((((unsigned)((s + 1) & 1) * 4 + gb) * 16 + gh) << 9) +
                                (((rr >> 2) * 32 + uu) << 2);
            asm volatile("global_store_dwordx4 %0, %1, off sc0 sc1"
                         :: "v"(dst), "v"(ck) : "memory");
        }

        if (s + 1 < T_) {
#pragma unroll
            for (int ni = 0; ni < 2; ++ni)
#pragma unroll
                for (int v = 0; v < 4; ++v) zxv[ni][v] = zxn[ni][v];   // waits zx here, post-publish
        }
    }

    // ---- final flush (s = T_-1) ----
#pragma unroll
    for (int v = 0; v < 4; ++v) {
        const int b = b0 + rr + v;
        const int ug = u0 + uu;
        int orig_t = rev ? ((T_ - 1 - pend_s + len_v[v]) & (T_ - 1)) : pend_s;
        if (cg == 0)
            out[((size_t)b * T_ + orig_t) * H_ + ug] = pend_hn[v];
        if (pend_s == len_v[v] - 1) {
            size_t fin = (size_t)B_ * T_ * H_;
            if (cg == 0) out[fin + (size_t)b * H_ + ug] = pend_cn[v];
            else         out[fin + (size_t)B_ * H_ + (size_t)b * H_ + ug] = pend_hn[v];
        }
    }
}

extern "C" void kernel_launch(void* const* d_in, const int* in_sizes, int n_in,
                              void* d_out, int out_size, void* d_ws, size_t ws_size,
                              hipStream_t stream)
{
    const float* x       = (const float*)d_in[0];
    const int*   lengths = (const int*)d_in[1];
    const float* c0      = (const float*)d_in[2];
    const float* h0      = (const float*)d_in[3];
    const float* Wi      = (const float*)d_in[4];
    const float* Wh      = (const float*)d_in[5];
    const float* bias    = (const float*)d_in[6];
    const int*   revp    = (const int*)d_in[7];
    float* out = (float*)d_out;

    char* ws = (char*)d_ws;
    const size_t OFF_WIT = 0;
    const size_t OFF_WHT = 2ull << 20;
    const size_t OFF_ZX  = 4ull << 20;
    const size_t OFF_HX  = OFF_ZX + (size_t)B_ * T_ * NG * 2;   // fp16 zx (128 MB)
    const size_t HX_BYTES = 2ull * 4 * 16 * 128 * 16;           // 256 KB tagged chunks
    const size_t NEED = OFF_HX + HX_BYTES;
    if (ws_size < NEED) return;

    unsigned short* WiT = (unsigned short*)(ws + OFF_WIT);
    unsigned short* WhT = (unsigned short*)(ws + OFF_WHT);
    _Float16* zx        = (_Float16*)(ws + OFF_ZX);
    unsigned int* hx    = (unsigned int*)(ws + OFF_HX);

    hipMemsetAsync(hx, 0, HX_BYTES, stream);   // invalidate tags each call
    dim3 gt(32, 8, 2);
    transpose_w<<<gt, 256, 0, stream>>>(Wi, Wh, WiT, WhT);
    dim3 g1(256, 16);
    zx_gemm<<<g1, 256, 0, stream>>>(x, lengths, WiT, bias, revp, zx);
    lstm_rec<<<64, 256, 0, stream>>>(zx, WhT, c0, h0, lengths, revp, out, hx);
}

// Round 9
// 2308.959 us; speedup vs baseline: 1.1870x; 1.1870x over previous
//
#include <hip/hip_runtime.h>

#define B_ 64
#define T_ 512
#define D_ 512
#define H_ 512
#define NG 2048  // 4H

typedef __attribute__((ext_vector_type(8))) short short8;
typedef __attribute__((ext_vector_type(4))) float floatx4;
typedef __attribute__((ext_vector_type(4))) unsigned int uintx4;

static __device__ __forceinline__ unsigned short f2bf(float f) {
    unsigned int u = __float_as_uint(f);
    return (unsigned short)((u + 0x7FFFu + ((u >> 16) & 1u)) >> 16);  // RNE
}

static __device__ __forceinline__ short8 pack8(float4 a, float4 b) {
    short8 r;
    r[0] = (short)f2bf(a.x); r[1] = (short)f2bf(a.y);
    r[2] = (short)f2bf(a.z); r[3] = (short)f2bf(a.w);
    r[4] = (short)f2bf(b.x); r[5] = (short)f2bf(b.y);
    r[6] = (short)f2bf(b.z); r[7] = (short)f2bf(b.w);
    return r;
}

static __device__ __forceinline__ float sigm(float x) { return 1.0f / (1.0f + __expf(-x)); }
static __device__ __forceinline__ float tanh_(float x) {
    float e = __expf(2.0f * x);
    return 1.0f - 2.0f / (e + 1.0f);
}

// ---- transpose Wi/Wh ([512][2048] f32) -> bf16 [2048][512], LDS-tiled ----
__global__ __launch_bounds__(256) void transpose_w(
    const float* __restrict__ Wi, const float* __restrict__ Wh,
    unsigned short* __restrict__ WiT, unsigned short* __restrict__ WhT)
{
    __shared__ float tile[64][65];
    const float* src = blockIdx.z ? Wh : Wi;
    unsigned short* dst = blockIdx.z ? WhT : WiT;
    const int n0 = blockIdx.x * 64, k0 = blockIdx.y * 64;
    const int cx = threadIdx.x & 63, ry = threadIdx.x >> 6;
#pragma unroll
    for (int i = 0; i < 16; ++i) {
        int k = ry * 16 + i;
        tile[k][cx] = src[(size_t)(k0 + k) * NG + n0 + cx];
    }
    __syncthreads();
#pragma unroll
    for (int i = 0; i < 16; ++i) {
        int n = ry * 16 + i;
        dst[(size_t)(n0 + n) * D_ + k0 + cx] = f2bf(tile[cx][n]);
    }
}

// ---- zx[b][t][4H] (fp16) = flip(x) @ Wi + b ; 128x128 tile, 4 waves ----
__global__ __launch_bounds__(256) void zx_gemm(
    const float* __restrict__ x, const int* __restrict__ lengths,
    const unsigned short* __restrict__ WiT, const float* __restrict__ bias,
    const int* __restrict__ revp, _Float16* __restrict__ zx)
{
    __shared__ unsigned short a_lds[128][40];
    __shared__ unsigned short b_lds[128][40];

    const int mt = blockIdx.x, nt = blockIdx.y;
    const int tid = threadIdx.x;
    const int lane = tid & 63, w = tid >> 6;
    const int wm = w & 1, wn = w >> 1;

    const int b = mt >> 2;
    const int len = lengths[b];
    const int rev = revp[0];

    const int r = tid >> 1;
    const int kh = (tid & 1) << 4;
    const int t = ((mt & 3) << 7) + r;
    const int src_t = rev ? ((T_ - 1 - t + len) & (T_ - 1)) : t;
    const float* arow = x + ((size_t)b * T_ + src_t) * D_;
    const unsigned short* brow = WiT + (size_t)(nt * 128 + r) * D_;

    floatx4 acc[4][4];
#pragma unroll
    for (int i = 0; i < 4; ++i)
#pragma unroll
        for (int j = 0; j < 4; ++j) acc[i][j] = (floatx4){0.f, 0.f, 0.f, 0.f};

    for (int kt = 0; kt < D_ / 32; ++kt) {
        const float4* ap = (const float4*)(arow + kt * 32 + kh);
        float4 a0 = ap[0], a1 = ap[1], a2 = ap[2], a3 = ap[3];
        const uint4* bp = (const uint4*)(brow + kt * 32 + kh);
        uint4 bq0 = bp[0], bq1 = bp[1];
        *(short8*)&a_lds[r][kh]     = pack8(a0, a1);
        *(short8*)&a_lds[r][kh + 8] = pack8(a2, a3);
        *(uint4*)&b_lds[r][kh]     = bq0;
        *(uint4*)&b_lds[r][kh + 8] = bq1;
        __syncthreads();

        short8 af[4], bfr[4];
#pragma unroll
        for (int mi = 0; mi < 4; ++mi)
            af[mi] = *(const short8*)&a_lds[wm * 64 + mi * 16 + (lane & 15)][(lane >> 4) << 3];
#pragma unroll
        for (int ni = 0; ni < 4; ++ni)
            bfr[ni] = *(const short8*)&b_lds[wn * 64 + ni * 16 + (lane & 15)][(lane >> 4) << 3];
#pragma unroll
        for (int mi = 0; mi < 4; ++mi)
#pragma unroll
            for (int ni = 0; ni < 4; ++ni)
                acc[mi][ni] = __builtin_amdgcn_mfma_f32_16x16x32_bf16(af[mi], bfr[ni], acc[mi][ni], 0, 0, 0);
        __syncthreads();
    }

#pragma unroll
    for (int mi = 0; mi < 4; ++mi) {
#pragma unroll
        for (int ni = 0; ni < 4; ++ni) {
            int row = wm * 64 + mi * 16 + ((lane >> 4) << 2);
            int col = nt * 128 + wn * 64 + ni * 16 + (lane & 15);
            float bv = bias[col];
            size_t base = (size_t)(mt * 128 + row) * NG + col;
#pragma unroll
            for (int v = 0; v < 4; ++v)
                zx[base + (size_t)v * NG] = (_Float16)(acc[mi][ni][v] + bv);
        }
    }
}

// ---- persistent LSTM recurrence ----
// 64 blocks = 8 batch-groups(8 batches) x 8 h-slices(64 units). 512 thr = 8 waves;
// wave w owns 32 gate-cols (4 gates x 8 units), full K=512 in regs (bw 128 VGPR).
// Exchange: self-validating 16B chunks {batch-quad bf16, tag, pad}, fire-forget.
// ONLY WAVE 0 polls+loads the whole group h (16KB tagged): light 8-probe detect,
// then per-lane tag-verified 256B load + transpose + ds_write. Other waves idle at
// the block barrier (zero poll traffic).
__global__ __launch_bounds__(512, 2) void lstm_rec(
    const _Float16* __restrict__ zx, const unsigned short* __restrict__ WhT,
    const float* __restrict__ c0, const float* __restrict__ h0,
    const int* __restrict__ lengths, const int* __restrict__ revp,
    float* __restrict__ out, unsigned int* __restrict__ hx)
{
    __shared__ unsigned short h_lds[16][520];   // rows 0-7 = batches, 8-15 zero

    const int bid = blockIdx.x;
    const int gb = bid & 7, gh = bid >> 3;
    const int tid = threadIdx.x;
    const int lane = tid & 63, w = tid >> 6;
    const int b0 = gb * 8, u0 = gh * 64;
    const int rev = revp[0];

    const int colh = lane & 15;
    const int rr = (lane >> 4) << 2;   // 0,4,8,12 (valid batch rows: rr<8)
    const int rb = rr & 7;             // clamped batch base for safe loads
    const int cg = colh >> 3;          // gate-pair selector (0:{i,g} 1:{f,o})
    const int cu = colh & 7;
    const int uu = w * 8 + cu;         // unit within block (0..63)
    const int khw = (lane >> 4) << 3;
    const bool rowok = (rr < 8);

    int len_v[4]; float c[4];
#pragma unroll
    for (int v = 0; v < 4; ++v) {
        len_v[v] = lengths[b0 + rb + v];
        c[v] = rowok ? c0[(size_t)(b0 + rr + v) * H_ + u0 + uu] : 0.0f;
    }

    // Wh fragments: bw[kk][ni] for gate = ni*2+cg, unit = u0+uu
    short8 bw[16][2];
#pragma unroll
    for (int ni = 0; ni < 2; ++ni) {
        const unsigned short* src = WhT + (size_t)((ni * 2 + cg) * H_ + u0 + uu) * D_ + khw;
#pragma unroll
        for (int kk = 0; kk < 16; ++kk)
            bw[kk][ni] = *(const short8*)(src + kk * 32);
    }

    float zxv[2][4];
#pragma unroll
    for (int ni = 0; ni < 2; ++ni)
#pragma unroll
        for (int v = 0; v < 4; ++v)
            zxv[ni][v] = (float)zx[((size_t)(b0 + rb + v) * T_) * NG + (ni * 2 + cg) * H_ + u0 + uu];

    // zero LDS (rows 8-15 stay zero forever)
    for (int i = tid; i < 16 * 520; i += 512) ((unsigned short*)h_lds)[i] = 0;
    __syncthreads();

    for (int s = 0; s < T_; ++s) {
        // ---- wave0: stage group h(s)[8][512] -> LDS ----
        if (w == 0) {
            if (s == 0) {
#pragma unroll
                for (int b = 0; b < 8; ++b) {
                    const float* hp = h0 + (size_t)(b0 + b) * H_ + lane * 8;
                    float4 f0 = *(const float4*)hp;
                    float4 f1 = *(const float4*)(hp + 4);
                    *(short8*)&h_lds[b][lane * 8] = pack8(f0, f1);
                }
            } else {
                const unsigned int tg = (unsigned int)s;
                const unsigned int grp = ((unsigned)(s & 1) * 8 + gb) * 1024;
                // light probe: 8 producer "last chunks" (p = lane&7)
                const unsigned int* pp = hx + (size_t)(grp + (lane & 7) * 128 + 127) * 4 + 2;
                for (;;) {
                    unsigned int tv;
                    asm volatile("global_load_dword %0, %1, off sc0 sc1\n\t"
                                 "s_waitcnt vmcnt(0)"
                                 : "=v"(tv) : "v"(pp) : "memory");
                    if (__all(tv == tg)) break;
                    __builtin_amdgcn_s_sleep(1);
                }
                // full load: 16 chunks/lane in 2 halves, tag-verified, transpose->LDS
#pragma unroll
                for (int half = 0; half < 2; ++half) {
                    const unsigned int* dp = hx + (size_t)(grp + lane * 16 + half * 8) * 4;
                    uintx4 k0, k1, k2, k3, k4, k5, k6, k7;
                    for (;;) {
                        asm volatile(
                            "global_load_dwordx4 %0, %8, off sc0 sc1\n\t"
                            "global_load_dwordx4 %1, %8, off offset:16 sc0 sc1\n\t"
                            "global_load_dwordx4 %2, %8, off offset:32 sc0 sc1\n\t"
                            "global_load_dwordx4 %3, %8, off offset:48 sc0 sc1\n\t"
                            "global_load_dwordx4 %4, %8, off offset:64 sc0 sc1\n\t"
                            "global_load_dwordx4 %5, %8, off offset:80 sc0 sc1\n\t"
                            "global_load_dwordx4 %6, %8, off offset:96 sc0 sc1\n\t"
                            "global_load_dwordx4 %7, %8, off offset:112 sc0 sc1\n\t"
                            "s_waitcnt vmcnt(0)"
                            : "=&v"(k0), "=&v"(k1), "=&v"(k2), "=&v"(k3),
                              "=&v"(k4), "=&v"(k5), "=&v"(k6), "=&v"(k7)
                            : "v"(dp) : "memory");
                        bool ok = (k0[2] == tg) & (k1[2] == tg) & (k2[2] == tg) & (k3[2] == tg) &
                                  (k4[2] == tg) & (k5[2] == tg) & (k6[2] == tg) & (k7[2] == tg);
                        if (ok) break;
                        __builtin_amdgcn_s_sleep(1);
                    }
                    // chunks c=0..7: unit = lane*8 + half*4 + (c>>1), quad q = c&1
                    unsigned int pay[8][2];
                    pay[0][0] = k0[0]; pay[0][1] = k0[1];
                    pay[1][0] = k1[0]; pay[1][1] = k1[1];
                    pay[2][0] = k2[0]; pay[2][1] = k2[1];
                    pay[3][0] = k3[0]; pay[3][1] = k3[1];
                    pay[4][0] = k4[0]; pay[4][1] = k4[1];
                    pay[5][0] = k5[0]; pay[5][1] = k5[1];
                    pay[6][0] = k6[0]; pay[6][1] = k6[1];
                    pay[7][0] = k7[0]; pay[7][1] = k7[1];
#pragma unroll
                    for (int b = 0; b < 8; ++b) {
                        const int q = b >> 2, hi = (b >> 1) & 1, sh = (b & 1) * 16;
                        unsigned int x0 = (pay[0 * 2 + q][hi] >> sh) & 0xffffu;
                        unsigned int x1 = (pay[1 * 2 + q][hi] >> sh) & 0xffffu;
                        unsigned int x2 = (pay[2 * 2 + q][hi] >> sh) & 0xffffu;
                        unsigned int x3 = (pay[3 * 2 + q][hi] >> sh) & 0xffffu;
                        uint2 d;
                        d.x = x0 | (x1 << 16);
                        d.y = x2 | (x3 << 16);
                        *(uint2*)&h_lds[b][lane * 8 + half * 4] = d;
                    }
                }
            }
        }
        __syncthreads();   // (A) h_lds ready

        // ---- z = h @ Wh (full K per wave, 32 MFMA) ----
        floatx4 acc[2];
        acc[0] = (floatx4){0.f, 0.f, 0.f, 0.f};
        acc[1] = (floatx4){0.f, 0.f, 0.f, 0.f};
#pragma unroll
        for (int kk = 0; kk < 16; ++kk) {
            short8 af = *(const short8*)&h_lds[lane & 15][kk * 32 + khw];
            acc[0] = __builtin_amdgcn_mfma_f32_16x16x32_bf16(af, bw[kk][0], acc[0], 0, 0, 0);
            acc[1] = __builtin_amdgcn_mfma_f32_16x16x32_bf16(af, bw[kk][1], acc[1], 0, 0, 0);
        }
        __syncthreads();   // (B) h_lds reads done; stager may overwrite next iter

        // ---- gates ----
        float hn_v[4], cn_v[4];
#pragma unroll
        for (int v = 0; v < 4; ++v) {
            float own0 = acc[0][v] + zxv[0][v];        // gate cg
            float own1 = acc[1][v] + zxv[1][v];        // gate 2+cg
            float oth0 = __shfl_xor(own0, 8);          // gate 1-cg
            float oth1 = __shfl_xor(own1, 8);          // gate 3-cg
            float zi = cg ? oth0 : own0;
            float zf = cg ? own0 : oth0;
            float zg = cg ? oth1 : own1;
            float zo = cg ? own1 : oth1;
            float ig = sigm(zi), fg = sigm(zf);
            float gg = tanh_(zg), og = sigm(zo);
            float cn = fg * c[v] + ig * gg;
            float hn = og * tanh_(cn);
            c[v] = cn; cn_v[v] = cn; hn_v[v] = hn;
        }

        // ---- publish: fire-and-forget self-validating chunk (cg==1, valid rows) ----
        if (cg == 1 && rowok && s + 1 < T_) {
            uintx4 ck;
            ck[0] = (unsigned int)f2bf(hn_v[0]) | ((unsigned int)f2bf(hn_v[1]) << 16);
            ck[1] = (unsigned int)f2bf(hn_v[2]) | ((unsigned int)f2bf(hn_v[3]) << 16);
            ck[2] = (unsigned int)(s + 1); ck[3] = 0u;
            unsigned int* dst = hx +
                (size_t)((((unsigned)((s + 1) & 1) * 8 + gb) * 1024 + (u0 + uu) * 2 + (rr >> 2))) * 4;
            asm volatile("global_store_dwordx4 %0, %1, off sc0 sc1"
                         :: "v"(dst), "v"(ck) : "memory");
        }

        // ---- off-path: out stores + zx prefetch (drain under next poll) ----
        if (rowok) {
#pragma unroll
            for (int v = 0; v < 4; ++v) {
                const int b = b0 + rr + v;
                const int ug = u0 + uu;
                int orig_t = rev ? ((T_ - 1 - s + len_v[v]) & (T_ - 1)) : s;
                if (cg == 0)
                    out[((size_t)b * T_ + orig_t) * H_ + ug] = hn_v[v];
                if (s == len_v[v] - 1) {
                    size_t fin = (size_t)B_ * T_ * H_;
                    if (cg == 0) out[fin + (size_t)b * H_ + ug] = cn_v[v];
                    else         out[fin + (size_t)B_ * H_ + (size_t)b * H_ + ug] = hn_v[v];
                }
            }
        }
        if (s + 1 < T_) {
#pragma unroll
            for (int ni = 0; ni < 2; ++ni)
#pragma unroll
                for (int v = 0; v < 4; ++v)
                    zxv[ni][v] = (float)zx[((size_t)(b0 + rb + v) * T_ + s + 1) * NG +
                                           (ni * 2 + cg) * H_ + u0 + uu];
        }
    }
}

extern "C" void kernel_launch(void* const* d_in, const int* in_sizes, int n_in,
                              void* d_out, int out_size, void* d_ws, size_t ws_size,
                              hipStream_t stream)
{
    const float* x       = (const float*)d_in[0];
    const int*   lengths = (const int*)d_in[1];
    const float* c0      = (const float*)d_in[2];
    const float* h0      = (const float*)d_in[3];
    const float* Wi      = (const float*)d_in[4];
    const float* Wh      = (const float*)d_in[5];
    const float* bias    = (const float*)d_in[6];
    const int*   revp    = (const int*)d_in[7];
    float* out = (float*)d_out;

    char* ws = (char*)d_ws;
    const size_t OFF_WIT = 0;
    const size_t OFF_WHT = 2ull << 20;
    const size_t OFF_ZX  = 4ull << 20;
    const size_t OFF_HX  = OFF_ZX + (size_t)B_ * T_ * NG * 2;   // fp16 zx (128 MB)
    const size_t HX_BYTES = 2ull * 8 * 1024 * 16;               // 256 KB tagged chunks
    const size_t NEED = OFF_HX + HX_BYTES;
    if (ws_size < NEED) return;

    unsigned short* WiT = (unsigned short*)(ws + OFF_WIT);
    unsigned short* WhT = (unsigned short*)(ws + OFF_WHT);
    _Float16* zx        = (_Float16*)(ws + OFF_ZX);
    unsigned int* hx    = (unsigned int*)(ws + OFF_HX);

    hipMemsetAsync(hx, 0, HX_BYTES, stream);   // invalidate tags each call
    dim3 gt(32, 8, 2);
    transpose_w<<<gt, 256, 0, stream>>>(Wi, Wh, WiT, WhT);
    dim3 g1(256, 16);
    zx_gemm<<<g1, 256, 0, stream>>>(x, lengths, WiT, bias, revp, zx);
    lstm_rec<<<64, 512, 0, stream>>>(zx, WhT, c0, h0, lengths, revp, out, hx);
}

// Round 10
// 2035.728 us; speedup vs baseline: 1.3463x; 1.1342x over previous
//
#include <hip/hip_runtime.h>

#define B_ 64
#define T_ 512
#define D_ 512
#define H_ 512
#define NG 2048  // 4H

typedef __attribute__((ext_vector_type(8))) short short8;
typedef __attribute__((ext_vector_type(4))) float floatx4;
typedef __attribute__((ext_vector_type(4))) unsigned int uintx4;

static __device__ __forceinline__ unsigned short f2bf(float f) {
    unsigned int u = __float_as_uint(f);
    return (unsigned short)((u + 0x7FFFu + ((u >> 16) & 1u)) >> 16);  // RNE
}

static __device__ __forceinline__ short8 pack8(float4 a, float4 b) {
    short8 r;
    r[0] = (short)f2bf(a.x); r[1] = (short)f2bf(a.y);
    r[2] = (short)f2bf(a.z); r[3] = (short)f2bf(a.w);
    r[4] = (short)f2bf(b.x); r[5] = (short)f2bf(b.y);
    r[6] = (short)f2bf(b.z); r[7] = (short)f2bf(b.w);
    return r;
}

static __device__ __forceinline__ float sigm(float x) { return 1.0f / (1.0f + __expf(-x)); }
static __device__ __forceinline__ float tanh_(float x) {
    float e = __expf(2.0f * x);
    return 1.0f - 2.0f / (e + 1.0f);
}

// raw barrier: LDS-drain + s_barrier, NO vmcnt drain (keeps stores/loads in flight)
#define BAR_RAW() do { asm volatile("s_waitcnt lgkmcnt(0)" ::: "memory"); \
                       __builtin_amdgcn_s_barrier(); } while (0)

// ---- transpose Wi/Wh ([512][2048] f32) -> bf16 [2048][512], LDS-tiled ----
__global__ __launch_bounds__(256) void transpose_w(
    const float* __restrict__ Wi, const float* __restrict__ Wh,
    unsigned short* __restrict__ WiT, unsigned short* __restrict__ WhT)
{
    __shared__ float tile[64][65];
    const float* src = blockIdx.z ? Wh : Wi;
    unsigned short* dst = blockIdx.z ? WhT : WiT;
    const int n0 = blockIdx.x * 64, k0 = blockIdx.y * 64;
    const int cx = threadIdx.x & 63, ry = threadIdx.x >> 6;
#pragma unroll
    for (int i = 0; i < 16; ++i) {
        int k = ry * 16 + i;
        tile[k][cx] = src[(size_t)(k0 + k) * NG + n0 + cx];
    }
    __syncthreads();
#pragma unroll
    for (int i = 0; i < 16; ++i) {
        int n = ry * 16 + i;
        dst[(size_t)(n0 + n) * D_ + k0 + cx] = f2bf(tile[cx][n]);
    }
}

// ---- zx[b][t][4H] (fp16) = flip(x) @ Wi + b ; 128x128 tile, 4 waves ----
__global__ __launch_bounds__(256) void zx_gemm(
    const float* __restrict__ x, const int* __restrict__ lengths,
    const unsigned short* __restrict__ WiT, const float* __restrict__ bias,
    const int* __restrict__ revp, _Float16* __restrict__ zx)
{
    __shared__ unsigned short a_lds[128][40];
    __shared__ unsigned short b_lds[128][40];

    const int mt = blockIdx.x, nt = blockIdx.y;
    const int tid = threadIdx.x;
    const int lane = tid & 63, w = tid >> 6;
    const int wm = w & 1, wn = w >> 1;

    const int b = mt >> 2;
    const int len = lengths[b];
    const int rev = revp[0];

    const int r = tid >> 1;
    const int kh = (tid & 1) << 4;
    const int t = ((mt & 3) << 7) + r;
    const int src_t = rev ? ((T_ - 1 - t + len) & (T_ - 1)) : t;
    const float* arow = x + ((size_t)b * T_ + src_t) * D_;
    const unsigned short* brow = WiT + (size_t)(nt * 128 + r) * D_;

    floatx4 acc[4][4];
#pragma unroll
    for (int i = 0; i < 4; ++i)
#pragma unroll
        for (int j = 0; j < 4; ++j) acc[i][j] = (floatx4){0.f, 0.f, 0.f, 0.f};

    for (int kt = 0; kt < D_ / 32; ++kt) {
        const float4* ap = (const float4*)(arow + kt * 32 + kh);
        float4 a0 = ap[0], a1 = ap[1], a2 = ap[2], a3 = ap[3];
        const uint4* bp = (const uint4*)(brow + kt * 32 + kh);
        uint4 bq0 = bp[0], bq1 = bp[1];
        *(short8*)&a_lds[r][kh]     = pack8(a0, a1);
        *(short8*)&a_lds[r][kh + 8] = pack8(a2, a3);
        *(uint4*)&b_lds[r][kh]     = bq0;
        *(uint4*)&b_lds[r][kh + 8] = bq1;
        __syncthreads();

        short8 af[4], bfr[4];
#pragma unroll
        for (int mi = 0; mi < 4; ++mi)
            af[mi] = *(const short8*)&a_lds[wm * 64 + mi * 16 + (lane & 15)][(lane >> 4) << 3];
#pragma unroll
        for (int ni = 0; ni < 4; ++ni)
            bfr[ni] = *(const short8*)&b_lds[wn * 64 + ni * 16 + (lane & 15)][(lane >> 4) << 3];
#pragma unroll
        for (int mi = 0; mi < 4; ++mi)
#pragma unroll
            for (int ni = 0; ni < 4; ++ni)
                acc[mi][ni] = __builtin_amdgcn_mfma_f32_16x16x32_bf16(af[mi], bfr[ni], acc[mi][ni], 0, 0, 0);
        __syncthreads();
    }

#pragma unroll
    for (int mi = 0; mi < 4; ++mi) {
#pragma unroll
        for (int ni = 0; ni < 4; ++ni) {
            int row = wm * 64 + mi * 16 + ((lane >> 4) << 2);
            int col = nt * 128 + wn * 64 + ni * 16 + (lane & 15);
            float bv = bias[col];
            size_t base = (size_t)(mt * 128 + row) * NG + col;
#pragma unroll
            for (int v = 0; v < 4; ++v)
                zx[base + (size_t)v * NG] = (_Float16)(acc[mi][ni][v] + bv);
        }
    }
}

// ---- persistent LSTM recurrence ----
// 64 blocks = 8 batch-groups(8 batches) x 8 h-slices(64 units); group gb = bid&7
// -> all 8 blocks of a chain on ONE XCD (round-robin dispatch), sharing an L2.
// Exchange: self-validating 16B chunks {batch-quad bf16, tag, pad}. DOUBLE-PUBLISH:
// fast copy (sc0 only -> same-XCD L2, ~200cy RTT) + device copy (sc0 sc1 -> MALL,
// always correct). Consumer: per-thread 32B detect==data poll on the fast buffer,
// bounded retries, then device-path fallback (sticky if placement is wrong).
// All barriers are raw (no vmcnt drain) so out-stores/zx-loads stay in flight.
__global__ __launch_bounds__(512) void lstm_rec(
    const _Float16* __restrict__ zx, const unsigned short* __restrict__ WhT,
    const float* __restrict__ c0, const float* __restrict__ h0,
    const int* __restrict__ lengths, const int* __restrict__ revp,
    float* __restrict__ out, unsigned int* __restrict__ hx_fast,
    unsigned int* __restrict__ hx_dev)
{
    __shared__ unsigned short h_lds[16][520];   // rows 0-7 = batches, 8-15 zero

    const int bid = blockIdx.x;
    const int gb = bid & 7, gh = bid >> 3;      // gb == XCD under round-robin
    const int tid = threadIdx.x;
    const int lane = tid & 63, w = tid >> 6;
    const int b0 = gb * 8, u0 = gh * 64;
    const int rev = revp[0];

    const int colh = lane & 15;
    const int rr = (lane >> 4) << 2;   // 0,4,8,12 (valid batch rows: rr<8)
    const int rb = rr & 7;             // clamped (in-bounds) batch base
    const int cg = colh >> 3;          // gate-pair selector (0:{i,g} 1:{f,o})
    const int cu = colh & 7;
    const int uu = w * 8 + cu;         // unit within block (0..63)
    const int khw = (lane >> 4) << 3;
    const bool rowok = (rr < 8);

    int len_v[4]; float c[4];
#pragma unroll
    for (int v = 0; v < 4; ++v) {
        len_v[v] = lengths[b0 + rb + v];
        c[v] = c0[(size_t)(b0 + rb + v) * H_ + u0 + uu];   // in-bounds; unused if !rowok
    }

    // Wh fragments: bw[kk][ni] for gate = ni*2+cg, unit = u0+uu, full K=512
    short8 bw[16][2];
#pragma unroll
    for (int ni = 0; ni < 2; ++ni) {
        const unsigned short* src = WhT + (size_t)((ni * 2 + cg) * H_ + u0 + uu) * D_ + khw;
#pragma unroll
        for (int kk = 0; kk < 16; ++kk)
            bw[kk][ni] = *(const short8*)(src + kk * 32);
    }

    float zxv[2][4];
#pragma unroll
    for (int ni = 0; ni < 2; ++ni)
#pragma unroll
        for (int v = 0; v < 4; ++v)
            zxv[ni][v] = (float)zx[((size_t)(b0 + rb + v) * T_) * NG + (ni * 2 + cg) * H_ + u0 + uu];

    // zero LDS once (rows 8-15 stay zero)
    for (int i = tid; i < 16 * 520; i += 512) ((unsigned short*)h_lds)[i] = 0;
    BAR_RAW();

    int use_fast = 1;

    for (int s = 0; s < T_; ++s) {
        // ---- stage h(s): thread tid owns unit tid (both batch-quads, 32B) ----
        if (s == 0) {
#pragma unroll
            for (int b = 0; b < 8; ++b)
                h_lds[b][tid] = f2bf(h0[(size_t)(b0 + b) * H_ + tid]);
        } else {
            const unsigned int tg = (unsigned int)s;
            const unsigned int cbase = (((unsigned)(s & 1) * 8 + gb) * 1024 + tid * 2) * 4;
            const unsigned int* fp = hx_fast + cbase;
            const unsigned int* dvp = hx_dev + cbase;
            uintx4 k0, k1;
            bool ok = false;
            if (use_fast) {
                int tries = 24;
                do {
                    asm volatile("global_load_dwordx4 %0, %2, off sc0\n\t"
                                 "global_load_dwordx4 %1, %2, off offset:16 sc0\n\t"
                                 "s_waitcnt vmcnt(0)"
                                 : "=&v"(k0), "=&v"(k1) : "v"(fp) : "memory");
                    ok = (k0[2] == tg) & (k1[2] == tg);
                } while (!ok && --tries);
            }
            if (!ok) {
                bool first = true;
                for (;;) {
                    asm volatile("global_load_dwordx4 %0, %2, off sc0 sc1\n\t"
                                 "global_load_dwordx4 %1, %2, off offset:16 sc0 sc1\n\t"
                                 "s_waitcnt vmcnt(0)"
                                 : "=&v"(k0), "=&v"(k1) : "v"(dvp) : "memory");
                    if ((k0[2] == tg) & (k1[2] == tg)) {
                        if (first) use_fast = 0;   // placement wrong: data was old, L2 missed it
                        break;
                    }
                    first = false;
                    __builtin_amdgcn_s_sleep(1);
                }
            }
            h_lds[0][tid] = (unsigned short)(k0[0] & 0xffffu);
            h_lds[1][tid] = (unsigned short)(k0[0] >> 16);
            h_lds[2][tid] = (unsigned short)(k0[1] & 0xffffu);
            h_lds[3][tid] = (unsigned short)(k0[1] >> 16);
            h_lds[4][tid] = (unsigned short)(k1[0] & 0xffffu);
            h_lds[5][tid] = (unsigned short)(k1[0] >> 16);
            h_lds[6][tid] = (unsigned short)(k1[1] & 0xffffu);
            h_lds[7][tid] = (unsigned short)(k1[1] >> 16);
        }
        BAR_RAW();   // (A) h_lds ready — no vmcnt drain

        // ---- zx prefetch for s+1 (drains under MFMA+gates) ----
        float zxn[2][4];
        if (s + 1 < T_) {
#pragma unroll
            for (int ni = 0; ni < 2; ++ni)
#pragma unroll
                for (int v = 0; v < 4; ++v)
                    zxn[ni][v] = (float)zx[((size_t)(b0 + rb + v) * T_ + s + 1) * NG +
                                           (ni * 2 + cg) * H_ + u0 + uu];
        }

        // ---- z = h @ Wh (full K per wave, 32 MFMA) ----
        floatx4 acc[2];
        acc[0] = (floatx4){0.f, 0.f, 0.f, 0.f};
        acc[1] = (floatx4){0.f, 0.f, 0.f, 0.f};
#pragma unroll
        for (int kk = 0; kk < 16; ++kk) {
            short8 af = *(const short8*)&h_lds[lane & 15][kk * 32 + khw];
            acc[0] = __builtin_amdgcn_mfma_f32_16x16x32_bf16(af, bw[kk][0], acc[0], 0, 0, 0);
            acc[1] = __builtin_amdgcn_mfma_f32_16x16x32_bf16(af, bw[kk][1], acc[1], 0, 0, 0);
        }
        BAR_RAW();   // (B) h_lds released for next stage — no vmcnt drain

        // ---- gates ----
        float hn_v[4], cn_v[4];
#pragma unroll
        for (int v = 0; v < 4; ++v) {
            float own0 = acc[0][v] + zxv[0][v];        // gate cg
            float own1 = acc[1][v] + zxv[1][v];        // gate 2+cg
            float oth0 = __shfl_xor(own0, 8);          // gate 1-cg
            float oth1 = __shfl_xor(own1, 8);          // gate 3-cg
            float zi = cg ? oth0 : own0;
            float zf = cg ? own0 : oth0;
            float zg = cg ? oth1 : own1;
            float zo = cg ? own1 : oth1;
            float ig = sigm(zi), fg = sigm(zf);
            float gg = tanh_(zg), og = sigm(zo);
            float cn = fg * c[v] + ig * gg;
            float hn = og * tanh_(cn);
            c[v] = cn; cn_v[v] = cn; hn_v[v] = hn;
        }

        // ---- publish: fast (same-XCD L2) + device copy, both fire-and-forget ----
        if (cg == 1 && rowok && s + 1 < T_) {
            uintx4 ck;
            ck[0] = (unsigned int)f2bf(hn_v[0]) | ((unsigned int)f2bf(hn_v[1]) << 16);
            ck[1] = (unsigned int)f2bf(hn_v[2]) | ((unsigned int)f2bf(hn_v[3]) << 16);
            ck[2] = (unsigned int)(s + 1); ck[3] = 0u;
            const unsigned int co =
                (((unsigned)((s + 1) & 1) * 8 + gb) * 1024 + (u0 + uu) * 2 + (rr >> 2)) * 4;
            unsigned int* fdst = hx_fast + co;
            unsigned int* ddst = hx_dev + co;
            asm volatile("global_store_dwordx4 %0, %1, off sc0"
                         :: "v"(fdst), "v"(ck) : "memory");
            asm volatile("global_store_dwordx4 %0, %1, off sc0 sc1"
                         :: "v"(ddst), "v"(ck) : "memory");
        }

        // ---- off-path: out stores (drain under next poll / later barriers) ----
        if (rowok) {
#pragma unroll
            for (int v = 0; v < 4; ++v) {
                const int b = b0 + rr + v;
                const int ug = u0 + uu;
                int orig_t = rev ? ((T_ - 1 - s + len_v[v]) & (T_ - 1)) : s;
                if (cg == 0)
                    out[((size_t)b * T_ + orig_t) * H_ + ug] = hn_v[v];
                if (s == len_v[v] - 1) {
                    size_t fin = (size_t)B_ * T_ * H_;
                    if (cg == 0) out[fin + (size_t)b * H_ + ug] = cn_v[v];
                    else         out[fin + (size_t)B_ * H_ + (size_t)b * H_ + ug] = hn_v[v];
                }
            }
        }
        if (s + 1 < T_) {
#pragma unroll
            for (int ni = 0; ni < 2; ++ni)
#pragma unroll
                for (int v = 0; v < 4; ++v) zxv[ni][v] = zxn[ni][v];
        }
    }
}

extern "C" void kernel_launch(void* const* d_in, const int* in_sizes, int n_in,
                              void* d_out, int out_size, void* d_ws, size_t ws_size,
                              hipStream_t stream)
{
    const float* x       = (const float*)d_in[0];
    const int*   lengths = (const int*)d_in[1];
    const float* c0      = (const float*)d_in[2];
    const float* h0      = (const float*)d_in[3];
    const float* Wi      = (const float*)d_in[4];
    const float* Wh      = (const float*)d_in[5];
    const float* bias    = (const float*)d_in[6];
    const int*   revp    = (const int*)d_in[7];
    float* out = (float*)d_out;

    char* ws = (char*)d_ws;
    const size_t OFF_WIT = 0;
    const size_t OFF_WHT = 2ull << 20;
    const size_t OFF_ZX  = 4ull << 20;
    const size_t OFF_HXF = OFF_ZX + (size_t)B_ * T_ * NG * 2;   // fp16 zx (128 MB)
    const size_t HX_BYTES = 2ull * 8 * 1024 * 16;               // 256 KB per buffer
    const size_t OFF_HXD = OFF_HXF + HX_BYTES;
    const size_t NEED = OFF_HXD + HX_BYTES;
    if (ws_size < NEED) return;

    unsigned short* WiT = (unsigned short*)(ws + OFF_WIT);
    unsigned short* WhT = (unsigned short*)(ws + OFF_WHT);
    _Float16* zx        = (_Float16*)(ws + OFF_ZX);
    unsigned int* hxf   = (unsigned int*)(ws + OFF_HXF);
    unsigned int* hxd   = (unsigned int*)(ws + OFF_HXD);

    hipMemsetAsync(hxf, 0, 2 * HX_BYTES, stream);   // invalidate tags each call
    dim3 gt(32, 8, 2);
    transpose_w<<<gt, 256, 0, stream>>>(Wi, Wh, WiT, WhT);
    dim3 g1(256, 16);
    zx_gemm<<<g1, 256, 0, stream>>>(x, lengths, WiT, bias, revp, zx);
    lstm_rec<<<64, 512, 0, stream>>>(zx, WhT, c0, h0, lengths, revp, out, hxf, hxd);
}